// Round 1
// baseline (247.209 us; speedup 1.0000x reference)
//
#include <hip/hip_runtime.h>
#include <hip/hip_bf16.h>
#include <stdint.h>

// SymmetricLoss: symmetric InfoNCE over cosine logits.
// loss = mean_i[ 0.5*(log rowsum_i + log colsum_i) - S_ii ],
// S = Xn·Ynᵀ / tau, rowsum_i = Σ_j exp(S_ij), colsum_j = Σ_i exp(S_ij).
// |S|<=2 so exp needs no max-subtraction (no online softmax needed).

#define NROWS 8192
#define DDIM  512
#define TAU_INV 2.0f

typedef __bf16 bf16x8 __attribute__((ext_vector_type(8)));
typedef __bf16 bf16x4 __attribute__((ext_vector_type(4)));
typedef float  f32x4  __attribute__((ext_vector_type(4)));

// ---------------- kernel 1: row-normalize x,y -> bf16 ----------------
__global__ __launch_bounds__(256) void normalize_kernel(
    const float* __restrict__ x, const float* __restrict__ y,
    __bf16* __restrict__ xn, __bf16* __restrict__ yn) {
  const int wave = threadIdx.x >> 6;
  const int lane = threadIdx.x & 63;
  const int row  = blockIdx.x * 4 + wave;   // 0..16383: first 8192 = x, rest = y
  const float* src;
  __bf16* dst;
  if (row < NROWS) { src = x + (size_t)row * DDIM;           dst = xn + (size_t)row * DDIM; }
  else             { src = y + (size_t)(row - NROWS) * DDIM; dst = yn + (size_t)(row - NROWS) * DDIM; }

  const float4* s4 = (const float4*)src;
  float4 v0 = s4[lane];        // elems [4*lane, 4*lane+4)
  float4 v1 = s4[lane + 64];   // elems [256+4*lane, ...)
  float ss = v0.x*v0.x + v0.y*v0.y + v0.z*v0.z + v0.w*v0.w
           + v1.x*v1.x + v1.y*v1.y + v1.z*v1.z + v1.w*v1.w;
  #pragma unroll
  for (int off = 1; off < 64; off <<= 1) ss += __shfl_xor(ss, off);
  const float rn = 1.0f / fmaxf(sqrtf(ss), 1e-8f);

  bf16x4 o0, o1;
  o0[0]=(__bf16)(v0.x*rn); o0[1]=(__bf16)(v0.y*rn); o0[2]=(__bf16)(v0.z*rn); o0[3]=(__bf16)(v0.w*rn);
  o1[0]=(__bf16)(v1.x*rn); o1[1]=(__bf16)(v1.y*rn); o1[2]=(__bf16)(v1.z*rn); o1[3]=(__bf16)(v1.w*rn);
  *(bf16x4*)(dst + 4*lane)       = o0;
  *(bf16x4*)(dst + 256 + 4*lane) = o1;
}

// ---------------- kernel 2: fused GEMM + exp + row/col sums ----------------
// 128x128 tile per block, BK=64, 4 waves in 2x2, each wave 64x64 (4x4 MFMA 16x16x32).
// LDS layout is XOR-swizzled via pre-swizzled GLOBAL source (rule #21): LDS dest
// stays linear for global_load_lds; 16B chunk index cc within a row holds global
// chunk cc^(row&7). ds_read applies the same XOR -> conflict-free b128 reads.
__global__ __launch_bounds__(256) void gemm_exp_kernel(
    const __bf16* __restrict__ Xn, const __bf16* __restrict__ Yn,
    float* __restrict__ rowsum, float* __restrict__ colsum,
    float* __restrict__ diag) {
  __shared__ __bf16 As[128 * 64];
  __shared__ __bf16 Bs[128 * 64];

  const int bi = blockIdx.y;          // row tile
  const int bj = blockIdx.x;          // col tile
  const int t    = threadIdx.x;
  const int lane = t & 63;
  const int w    = t >> 6;
  const int wr   = w >> 1;            // wave row 0..1
  const int wc   = w & 1;             // wave col 0..1

  f32x4 acc[4][4] = {};

  for (int kt = 0; kt < DDIM / 64; ++kt) {
    const int k0 = kt * 64;
    // stage A and B tiles: 1024 chunks of 16B each per tile, 4 per thread
    #pragma unroll
    for (int it = 0; it < 4; ++it) {
      const int c  = it * 256 + t;    // linear 16B chunk in LDS
      const int r  = c >> 3;          // tile row 0..127
      const int cc = c & 7;           // 16B chunk within row
      const int sc = cc ^ (r & 7);    // pre-swizzled source chunk
      const __bf16* ga = Xn + (size_t)(bi * 128 + r) * DDIM + k0 + sc * 8;
      const __bf16* gb = Yn + (size_t)(bj * 128 + r) * DDIM + k0 + sc * 8;
      __builtin_amdgcn_global_load_lds(
          (__attribute__((address_space(1))) void*)ga,
          (__attribute__((address_space(3))) void*)(As + c * 8), 16, 0, 0);
      __builtin_amdgcn_global_load_lds(
          (__attribute__((address_space(1))) void*)gb,
          (__attribute__((address_space(3))) void*)(Bs + c * 8), 16, 0, 0);
    }
    __syncthreads();   // drains vmcnt+lgkmcnt before barrier

    #pragma unroll
    for (int ks = 0; ks < 2; ++ks) {     // two K=32 steps per BK=64
      bf16x8 a[4], b[4];
      #pragma unroll
      for (int m = 0; m < 4; ++m) {
        const int r  = wr * 64 + m * 16 + (lane & 15);
        const int kc = ks * 4 + (lane >> 4);     // 16B chunk index in row
        const int sc = kc ^ (r & 7);
        a[m] = *(const bf16x8*)(As + r * 64 + sc * 8);
      }
      #pragma unroll
      for (int n = 0; n < 4; ++n) {
        const int r  = wc * 64 + n * 16 + (lane & 15);
        const int kc = ks * 4 + (lane >> 4);
        const int sc = kc ^ (r & 7);
        b[n] = *(const bf16x8*)(Bs + r * 64 + sc * 8);
      }
      #pragma unroll
      for (int m = 0; m < 4; ++m)
        #pragma unroll
        for (int n = 0; n < 4; ++n)
          acc[m][n] = __builtin_amdgcn_mfma_f32_16x16x32_bf16(a[m], b[n], acc[m][n], 0, 0, 0);
    }
    __syncthreads();   // protect LDS before next stage
  }

  // ---- epilogue ----
  // C layout (verified m89/m91): col = lane&15, row = (lane>>4)*4 + reg
  const int g   = lane >> 4;
  const int c15 = lane & 15;
  const int rowbase = bi * 128 + wr * 64;
  const int colbase = bj * 128 + wc * 64;

  // diag first (needs pre-exp scaled value); static reg indices only (rule #20)
  if (bi == bj && wr == wc) {
    #pragma unroll
    for (int m = 0; m < 4; ++m)
      #pragma unroll
      for (int r = 0; r < 4; ++r)
        if (c15 == g * 4 + r)
          diag[rowbase + m * 16 + c15] = TAU_INV * acc[m][m][r];
  }

  // exp in place
  #pragma unroll
  for (int m = 0; m < 4; ++m)
    #pragma unroll
    for (int n = 0; n < 4; ++n)
      #pragma unroll
      for (int r = 0; r < 4; ++r)
        acc[m][n][r] = __expf(TAU_INV * acc[m][n][r]);

  // row sums: reduce over cols (lane&15 within group) + n-fragments
  #pragma unroll
  for (int m = 0; m < 4; ++m) {
    #pragma unroll
    for (int r = 0; r < 4; ++r) {
      float v = acc[m][0][r] + acc[m][1][r] + acc[m][2][r] + acc[m][3][r];
      v += __shfl_xor(v, 1); v += __shfl_xor(v, 2);
      v += __shfl_xor(v, 4); v += __shfl_xor(v, 8);
      if (c15 == 0)
        atomicAdd(&rowsum[rowbase + m * 16 + g * 4 + r], v);
    }
  }
  // col sums: reduce over rows (groups) + m-fragments
  #pragma unroll
  for (int n = 0; n < 4; ++n) {
    float v = 0.0f;
    #pragma unroll
    for (int m = 0; m < 4; ++m)
      #pragma unroll
      for (int r = 0; r < 4; ++r)
        v += acc[m][n][r];
    v += __shfl_xor(v, 16); v += __shfl_xor(v, 32);
    if (lane < 16)
      atomicAdd(&colsum[colbase + n * 16 + lane], v);
  }
}

// ---------------- kernel 3: final scalar reduction ----------------
__global__ __launch_bounds__(256) void finalize_kernel(
    const float* __restrict__ rowsum, const float* __restrict__ colsum,
    const float* __restrict__ diag, float* __restrict__ out) {
  const int lane = threadIdx.x & 63;
  const int wave = threadIdx.x >> 6;
  float s = 0.0f;
  for (int i = threadIdx.x; i < NROWS; i += 256)
    s += 0.5f * (logf(rowsum[i]) + logf(colsum[i])) - diag[i];
  #pragma unroll
  for (int off = 1; off < 64; off <<= 1) s += __shfl_xor(s, off);
  __shared__ float red[4];
  if (lane == 0) red[wave] = s;
  __syncthreads();
  if (threadIdx.x == 0)
    out[0] = (red[0] + red[1] + red[2] + red[3]) * (1.0f / NROWS);
}

extern "C" void kernel_launch(void* const* d_in, const int* in_sizes, int n_in,
                              void* d_out, int out_size, void* d_ws, size_t ws_size,
                              hipStream_t stream) {
  const float* x = (const float*)d_in[0];
  const float* y = (const float*)d_in[1];
  float* out = (float*)d_out;

  char* ws = (char*)d_ws;
  __bf16* Xn = (__bf16*)ws;                              // 8 MB
  __bf16* Yn = Xn + (size_t)NROWS * DDIM;                // 8 MB
  float* rowsum = (float*)(ws + 2 * (size_t)NROWS * DDIM * sizeof(__bf16)); // @16MB
  float* colsum = rowsum + NROWS;
  float* diag   = colsum + NROWS;

  // ws is re-poisoned to 0xAA before every timed launch -> zero the accumulators
  hipMemsetAsync(rowsum, 0, 2 * NROWS * sizeof(float), stream);

  normalize_kernel<<<(2 * NROWS) / 4, 256, 0, stream>>>(x, y, Xn, Yn);
  gemm_exp_kernel<<<dim3(NROWS / 128, NROWS / 128), 256, 0, stream>>>(
      Xn, Yn, rowsum, colsum, diag);
  finalize_kernel<<<1, 256, 0, stream>>>(rowsum, colsum, diag, out);
}

// Round 2
// 195.466 us; speedup vs baseline: 1.2647x; 1.2647x over previous
//
#include <hip/hip_runtime.h>
#include <hip/hip_bf16.h>
#include <stdint.h>

// SymmetricLoss: symmetric InfoNCE over cosine logits.
// loss = mean_i[ 0.5*(log rowsum_i + log colsum_i) - S_ii ],
// S = Xn·Ynᵀ / tau.  |S|<=2 so exp needs no max subtraction.
//
// GEMM kernel: 256x256 tile, BK=64, 8 waves, 8-phase schedule (T3+T4) with
// counted vmcnt(6), raw s_barrier, setprio around MFMA (T5), XOR-swizzled
// LDS via pre-swizzled global source (T2, rule #21 both-sides involution).

#define NROWS 8192
#define DDIM  512
#define TAU_INV 2.0f
#define KT 8            // DDIM / 64 K-tiles

typedef __bf16 bf16x8 __attribute__((ext_vector_type(8)));
typedef __bf16 bf16x4 __attribute__((ext_vector_type(4)));
typedef float  f32x4  __attribute__((ext_vector_type(4)));

// ---------------- kernel 1: row-normalize x,y -> bf16 (+ zero accumulators) ----------------
__global__ __launch_bounds__(256) void normalize_kernel(
    const float* __restrict__ x, const float* __restrict__ y,
    __bf16* __restrict__ xn, __bf16* __restrict__ yn,
    float* __restrict__ rowsum, float* __restrict__ colsum,
    float* __restrict__ out) {
  const int idx = blockIdx.x * 256 + (int)threadIdx.x;
  if (idx < NROWS) { rowsum[idx] = 0.0f; colsum[idx] = 0.0f; }
  if (idx == 0) out[0] = 0.0f;

  const int wave = threadIdx.x >> 6;
  const int lane = threadIdx.x & 63;
  const int row  = blockIdx.x * 4 + wave;   // 0..16383: first 8192 = x, rest = y
  const float* src;
  __bf16* dst;
  if (row < NROWS) { src = x + (size_t)row * DDIM;           dst = xn + (size_t)row * DDIM; }
  else             { src = y + (size_t)(row - NROWS) * DDIM; dst = yn + (size_t)(row - NROWS) * DDIM; }

  const float4* s4 = (const float4*)src;
  float4 v0 = s4[lane];
  float4 v1 = s4[lane + 64];
  float ss = v0.x*v0.x + v0.y*v0.y + v0.z*v0.z + v0.w*v0.w
           + v1.x*v1.x + v1.y*v1.y + v1.z*v1.z + v1.w*v1.w;
  #pragma unroll
  for (int off = 1; off < 64; off <<= 1) ss += __shfl_xor(ss, off);
  const float rn = 1.0f / fmaxf(sqrtf(ss), 1e-8f);

  bf16x4 o0, o1;
  o0[0]=(__bf16)(v0.x*rn); o0[1]=(__bf16)(v0.y*rn); o0[2]=(__bf16)(v0.z*rn); o0[3]=(__bf16)(v0.w*rn);
  o1[0]=(__bf16)(v1.x*rn); o1[1]=(__bf16)(v1.y*rn); o1[2]=(__bf16)(v1.z*rn); o1[3]=(__bf16)(v1.w*rn);
  *(bf16x4*)(dst + 4*lane)       = o0;
  *(bf16x4*)(dst + 256 + 4*lane) = o1;
}

// Stage one 128-row half-tile (128 x 64 bf16 = 16 KB): 2 x global_load_lds(16B)/thread.
// LDS dest linear; source column-chunk pre-swizzled cc^(r&7) (involution, rule #21).
__device__ __forceinline__ void stage_half(const __bf16* __restrict__ M,
                                           int trow0, int kt, __bf16* lds, int tid) {
  const int r0 = tid >> 3;                       // 0..63
  const int sc = (tid & 7) ^ (r0 & 7);
  const __bf16* src = M + (size_t)(trow0 + r0) * DDIM + kt * 64 + sc * 8;
  __builtin_amdgcn_global_load_lds((__attribute__((address_space(1))) void*)src,
      (__attribute__((address_space(3))) void*)(lds + tid * 8), 16, 0, 0);
  __builtin_amdgcn_global_load_lds((__attribute__((address_space(1))) void*)(src + 64 * DDIM),
      (__attribute__((address_space(3))) void*)(lds + 4096 + tid * 8), 16, 0, 0);
}

// ---------------- kernel 2: fused 256^2-tile GEMM + exp + row/col sums ----------------
__global__ __launch_bounds__(512, 2) void gemm_exp_kernel(
    const __bf16* __restrict__ Xn, const __bf16* __restrict__ Yn,
    float* __restrict__ rowsum, float* __restrict__ colsum,
    float* __restrict__ diag) {
  // LDS: A bufs at 0 / 16384, B bufs at 32768 / 49152 (elems). 128 KiB total.
  __shared__ __bf16 sm[65536];

  const int tid  = threadIdx.x;
  const int lane = tid & 63;
  const int w    = tid >> 6;
  const int wr   = w >> 2;            // 0..1
  const int wc   = w & 3;             // 0..3
  const int bi = blockIdx.y, bj = blockIdx.x;

  const int l15 = lane & 15;
  const int g   = lane >> 4;          // 0..3
  const int lx  = lane & 7;
  const int sc0 = g ^ lx;             // swizzled chunk, ks=0
  const int sc1 = (4 + g) ^ lx;       // ks=1
  // interleaved wave sub-tiles: m-frag rows (m<4 -> A-lo, m>=4 -> A-hi)
  const int arow = wr * 64 + l15;     // + mi*16 (+128 for hi)
  const int brow = wc * 32 + l15;     // + ni*16 (+128 for hi)

  const int Ar = bi * 256;            // global row base (X)
  const int Br = bj * 256;            // global col base (Y)

  f32x4 acc[8][4] = {};

  // ---- prologue: 7 half-tiles, vmcnt 4 -> 6 (guide §5 template) ----
  stage_half(Xn, Ar,       0, sm + 0,                     tid);  // A-lo(0)
  stage_half(Yn, Br,       0, sm + 32768,                 tid);  // B-lo(0)
  stage_half(Yn, Br + 128, 0, sm + 32768 + 8192,          tid);  // B-hi(0)
  stage_half(Xn, Ar + 128, 0, sm + 8192,                  tid);  // A-hi(0)
  asm volatile("s_waitcnt vmcnt(4)" ::: "memory");
  stage_half(Xn, Ar,       1, sm + 16384,                 tid);  // A-lo(1)
  stage_half(Yn, Br,       1, sm + 32768 + 16384,         tid);  // B-lo(1)
  stage_half(Yn, Br + 128, 1, sm + 32768 + 16384 + 8192,  tid);  // B-hi(1)
  asm volatile("s_waitcnt vmcnt(6)" ::: "memory");
  __builtin_amdgcn_s_barrier();

  for (int t = 0; t < KT; ++t) {
    const int cbuf = t & 1, nbuf = cbuf ^ 1;
    const __bf16* As = sm + cbuf * 16384;
    const __bf16* Bs = sm + 32768 + cbuf * 16384;
    bf16x8 aq[2][4], blo[2][2], bhi[2][2];

    // ======== phase 1: acc[0..3][0..1]  (reads A-lo, B-lo) ========
    #pragma unroll
    for (int mi = 0; mi < 4; ++mi) {
      aq[0][mi] = *(const bf16x8*)(As + (arow + mi*16)*64 + sc0*8);
      aq[1][mi] = *(const bf16x8*)(As + (arow + mi*16)*64 + sc1*8);
    }
    #pragma unroll
    for (int ni = 0; ni < 2; ++ni) {
      blo[0][ni] = *(const bf16x8*)(Bs + (brow + ni*16)*64 + sc0*8);
      blo[1][ni] = *(const bf16x8*)(Bs + (brow + ni*16)*64 + sc1*8);
    }
    if (t < KT-1) stage_half(Xn, Ar + 128, t+1, sm + nbuf*16384 + 8192, tid);  // A-hi(t+1)
    __builtin_amdgcn_s_barrier();
    __builtin_amdgcn_s_setprio(1);
    #pragma unroll
    for (int mi = 0; mi < 4; ++mi)
      #pragma unroll
      for (int ni = 0; ni < 2; ++ni) {
        acc[mi][ni] = __builtin_amdgcn_mfma_f32_16x16x32_bf16(aq[0][mi], blo[0][ni], acc[mi][ni], 0,0,0);
        acc[mi][ni] = __builtin_amdgcn_mfma_f32_16x16x32_bf16(aq[1][mi], blo[1][ni], acc[mi][ni], 0,0,0);
      }
    __builtin_amdgcn_s_setprio(0);
    if (t == KT-1) asm volatile("s_waitcnt vmcnt(2)" ::: "memory");  // tail drain: B-hi(7) landed
    __builtin_amdgcn_s_barrier();

    // ======== phase 2: acc[0..3][2..3]  (reads B-hi; reuses aq) ========
    #pragma unroll
    for (int ni = 0; ni < 2; ++ni) {
      bhi[0][ni] = *(const bf16x8*)(Bs + (128 + brow + ni*16)*64 + sc0*8);
      bhi[1][ni] = *(const bf16x8*)(Bs + (128 + brow + ni*16)*64 + sc1*8);
    }
    if (t < KT-2) stage_half(Xn, Ar, t+2, sm + cbuf*16384, tid);               // A-lo(t+2)
    __builtin_amdgcn_s_barrier();
    __builtin_amdgcn_s_setprio(1);
    #pragma unroll
    for (int mi = 0; mi < 4; ++mi)
      #pragma unroll
      for (int ni = 0; ni < 2; ++ni) {
        acc[mi][2+ni] = __builtin_amdgcn_mfma_f32_16x16x32_bf16(aq[0][mi], bhi[0][ni], acc[mi][2+ni], 0,0,0);
        acc[mi][2+ni] = __builtin_amdgcn_mfma_f32_16x16x32_bf16(aq[1][mi], bhi[1][ni], acc[mi][2+ni], 0,0,0);
      }
    __builtin_amdgcn_s_setprio(0);
    if (t == KT-1) asm volatile("s_waitcnt vmcnt(0)" ::: "memory");  // tail drain: A-hi(7) landed
    __builtin_amdgcn_s_barrier();

    // ======== phase 3: acc[4..7][0..1]  (reads A-hi; reuses blo) ========
    #pragma unroll
    for (int mi = 0; mi < 4; ++mi) {
      aq[0][mi] = *(const bf16x8*)(As + (128 + arow + mi*16)*64 + sc0*8);
      aq[1][mi] = *(const bf16x8*)(As + (128 + arow + mi*16)*64 + sc1*8);
    }
    if (t < KT-2) stage_half(Yn, Br, t+2, sm + 32768 + cbuf*16384, tid);       // B-lo(t+2)
    __builtin_amdgcn_s_barrier();
    __builtin_amdgcn_s_setprio(1);
    #pragma unroll
    for (int mi = 0; mi < 4; ++mi)
      #pragma unroll
      for (int ni = 0; ni < 2; ++ni) {
        acc[4+mi][ni] = __builtin_amdgcn_mfma_f32_16x16x32_bf16(aq[0][mi], blo[0][ni], acc[4+mi][ni], 0,0,0);
        acc[4+mi][ni] = __builtin_amdgcn_mfma_f32_16x16x32_bf16(aq[1][mi], blo[1][ni], acc[4+mi][ni], 0,0,0);
      }
    __builtin_amdgcn_s_setprio(0);
    __builtin_amdgcn_s_barrier();

    // ======== phase 4: acc[4..7][2..3]  (no new reads) ========
    if (t < KT-2) stage_half(Yn, Br + 128, t+2, sm + 32768 + cbuf*16384 + 8192, tid); // B-hi(t+2)
    __builtin_amdgcn_s_barrier();
    __builtin_amdgcn_s_setprio(1);
    #pragma unroll
    for (int mi = 0; mi < 4; ++mi)
      #pragma unroll
      for (int ni = 0; ni < 2; ++ni) {
        acc[4+mi][2+ni] = __builtin_amdgcn_mfma_f32_16x16x32_bf16(aq[0][mi], bhi[0][ni], acc[4+mi][2+ni], 0,0,0);
        acc[4+mi][2+ni] = __builtin_amdgcn_mfma_f32_16x16x32_bf16(aq[1][mi], bhi[1][ni], acc[4+mi][2+ni], 0,0,0);
      }
    __builtin_amdgcn_s_setprio(0);
    // once-per-K-tile counted check: guarantee tile t+1 fully landed;
    // 3 newest half-tiles (for t+2) stay in flight (T4: never drain to 0 mid-loop).
    if (t < KT-2)       { asm volatile("s_waitcnt vmcnt(6)" ::: "memory"); }
    else if (t == KT-2) { asm volatile("s_waitcnt vmcnt(4)" ::: "memory"); }
    __builtin_amdgcn_s_barrier();
  }

  // ---------------- epilogue ----------------
  // C mapping (verified): row = frag_row_base + g*4 + reg, col = frag_col_base + l15
  int RL[8], CL[4];
  #pragma unroll
  for (int m = 0; m < 8; ++m) RL[m] = (m < 4) ? (wr*64 + m*16) : (128 + wr*64 + (m-4)*16);
  #pragma unroll
  for (int n = 0; n < 4; ++n) CL[n] = (n < 2) ? (wc*32 + n*16) : (128 + wc*32 + (n-2)*16);

  // diag (pre-exp logits), only diagonal blocks
  if (bi == bj) {
    #pragma unroll
    for (int m = 0; m < 8; ++m)
      #pragma unroll
      for (int n = 0; n < 4; ++n)
        #pragma unroll
        for (int r = 0; r < 4; ++r) {
          const int rl = RL[m] + g*4 + r, cl = CL[n] + l15;
          if (rl == cl) diag[bi*256 + rl] = TAU_INV * acc[m][n][r];
        }
  }

  // exp in place
  #pragma unroll
  for (int m = 0; m < 8; ++m)
    #pragma unroll
    for (int n = 0; n < 4; ++n)
      #pragma unroll
      for (int r = 0; r < 4; ++r)
        acc[m][n][r] = __expf(TAU_INV * acc[m][n][r]);

  // row sums: reduce over 4 n-frags + 16 cols (l15)
  #pragma unroll
  for (int m = 0; m < 8; ++m) {
    #pragma unroll
    for (int r = 0; r < 4; ++r) {
      float v = acc[m][0][r] + acc[m][1][r] + acc[m][2][r] + acc[m][3][r];
      v += __shfl_xor(v, 1); v += __shfl_xor(v, 2);
      v += __shfl_xor(v, 4); v += __shfl_xor(v, 8);
      if (l15 == 0) atomicAdd(&rowsum[Ar + RL[m] + g*4 + r], v);
    }
  }
  // col sums: reduce over 8 m-frags x 4 regs + 4 row-groups (g)
  #pragma unroll
  for (int n = 0; n < 4; ++n) {
    float v = 0.0f;
    #pragma unroll
    for (int m = 0; m < 8; ++m)
      #pragma unroll
      for (int r = 0; r < 4; ++r)
        v += acc[m][n][r];
    v += __shfl_xor(v, 16); v += __shfl_xor(v, 32);
    if (lane < 16) atomicAdd(&colsum[Br + CL[n] + l15], v);
  }
}

// ---------------- kernel 3: final scalar reduction (32 blocks, atomic) ----------------
__global__ __launch_bounds__(256) void finalize_kernel(
    const float* __restrict__ rowsum, const float* __restrict__ colsum,
    const float* __restrict__ diag, float* __restrict__ out) {
  const int i = blockIdx.x * 256 + (int)threadIdx.x;   // 32*256 == 8192 exactly
  float s = 0.5f * (logf(rowsum[i]) + logf(colsum[i])) - diag[i];
  #pragma unroll
  for (int off = 1; off < 64; off <<= 1) s += __shfl_xor(s, off);
  if ((threadIdx.x & 63) == 0) atomicAdd(out, s * (1.0f / NROWS));
}

extern "C" void kernel_launch(void* const* d_in, const int* in_sizes, int n_in,
                              void* d_out, int out_size, void* d_ws, size_t ws_size,
                              hipStream_t stream) {
  const float* x = (const float*)d_in[0];
  const float* y = (const float*)d_in[1];
  float* out = (float*)d_out;

  char* ws = (char*)d_ws;
  __bf16* Xn = (__bf16*)ws;                               // 8 MB
  __bf16* Yn = Xn + (size_t)NROWS * DDIM;                 // 8 MB
  float* rowsum = (float*)(ws + 2 * (size_t)NROWS * DDIM * sizeof(__bf16));
  float* colsum = rowsum + NROWS;
  float* diag   = colsum + NROWS;

  normalize_kernel<<<(2 * NROWS) / 4, 256, 0, stream>>>(x, y, Xn, Yn, rowsum, colsum, out);
  gemm_exp_kernel<<<dim3(NROWS / 256, NROWS / 256), 512, 0, stream>>>(
      Xn, Yn, rowsum, colsum, diag);
  finalize_kernel<<<32, 256, 0, stream>>>(rowsum, colsum, diag, out);
}